// Round 4
// baseline (4105.384 us; speedup 1.0000x reference)
//
#include <hip/hip_runtime.h>

#define CPG 8
#define NGRP 32
#define NB 16
#define HW 3136
#define HW2 1568     // HW in float2 units
#define N2 36
#define N3 120

typedef float vfloat2 __attribute__((ext_vector_type(2)));  // clang vector: nontemporal-ok
typedef float vfloat4 __attribute__((ext_vector_type(4)));

// index of pair (i,j), i<=j, in np.triu_indices(8) order
__host__ __device__ constexpr int idx2(int i, int j) {
    return i * CPG - i * (i - 1) / 2 + (j - i);
}
// index of triple (a,b,c), a<=b<=c, lexicographic
__host__ __device__ constexpr int idx3(int a, int b, int c) {
    int base = 0;
    for (int t = 0; t < a; ++t) { int m = CPG - t; base += m * (m + 1) / 2; }
    for (int t = a; t < b; ++t) base += CPG - t;
    return base + (c - b);
}

// accumulate feature value T (vfloat2) against wt[F][0..8): two uniform-address
// ds_read_b128 (broadcast, compile-time offsets), 16 v_fmac
#define ACCUM(F, T) do {                                                       \
    const vfloat4 wa = *reinterpret_cast<const vfloat4*>(&wt[(F)][0]);         \
    const vfloat4 wb = *reinterpret_cast<const vfloat4*>(&wt[(F)][4]);         \
    acc[0].x += wa.x * (T).x; acc[0].y += wa.x * (T).y;                        \
    acc[1].x += wa.y * (T).x; acc[1].y += wa.y * (T).y;                        \
    acc[2].x += wa.z * (T).x; acc[2].y += wa.z * (T).y;                        \
    acc[3].x += wa.w * (T).x; acc[3].y += wa.w * (T).y;                        \
    acc[4].x += wb.x * (T).x; acc[4].y += wb.x * (T).y;                        \
    acc[5].x += wb.y * (T).x; acc[5].y += wb.y * (T).y;                        \
    acc[6].x += wb.z * (T).x; acc[6].y += wb.z * (T).y;                        \
    acc[7].x += wb.w * (T).x; acc[7].y += wb.w * (T).y;                        \
} while (0)

__global__ __launch_bounds__(256) void hoaf_kernel(
    const float* __restrict__ x,
    const float* __restrict__ w1, const float* __restrict__ b1,
    const float* __restrict__ w2, const float* __restrict__ b2,
    const float* __restrict__ w3, const float* __restrict__ b3,
    float* __restrict__ out)
{
    // wt[f][o]: f 0-7 deg1, 8-43 deg2, 44-163 deg3, 164 = summed bias
    __shared__ __align__(16) float wt[165][8];

    const int tid   = threadIdx.x;
    const int chunk = blockIdx.x;   // 0..1 pixel halves
    const int g     = blockIdx.y;   // block-uniform group
    const int b     = blockIdx.z;

    for (int idx = tid; idx < 165 * 8; idx += 256) {
        const int f = idx >> 3, o = idx & 7;
        const int ch = g * CPG + o;
        float v;
        if (f < 8)        v = w1[ch * CPG + f];
        else if (f < 44)  v = w2[ch * N2 + (f - 8)];
        else if (f < 164) v = w3[ch * N3 + (f - 44)];
        else              v = b1[ch] + b2[ch] + b3[ch];
        wt[f][o] = v;
    }
    __syncthreads();

    const size_t base = ((size_t)(b * NGRP + g) * CPG) * HW;
    const vfloat2* x2 = (const vfloat2*)(x + base);
    vfloat2*       o2 = (vfloat2*)(out + base);

#pragma unroll 1
    for (int q = tid + chunk * 256; q < HW2; q += 512) {
        vfloat2 xv[CPG];
#pragma unroll
        for (int c = 0; c < CPG; ++c)
            xv[c] = __builtin_nontemporal_load(&x2[(size_t)c * HW2 + q]);

        vfloat2 acc[CPG];
        {
            const vfloat4 ba = *reinterpret_cast<const vfloat4*>(&wt[164][0]);
            const vfloat4 bb = *reinterpret_cast<const vfloat4*>(&wt[164][4]);
            acc[0] = {ba.x, ba.x}; acc[1] = {ba.y, ba.y};
            acc[2] = {ba.z, ba.z}; acc[3] = {ba.w, ba.w};
            acc[4] = {bb.x, bb.x}; acc[5] = {bb.y, bb.y};
            acc[6] = {bb.z, bb.z}; acc[7] = {bb.w, bb.w};
        }

        // degree 1
#pragma unroll
        for (int k = 0; k < CPG; ++k) ACCUM(k, xv[k]);

        // degree 2 & 3: pair product (i<=j) feeds triples (a<=i<=j)
#pragma unroll
        for (int i = 0; i < CPG; ++i) {
#pragma unroll
            for (int j = i; j < CPG; ++j) {
                vfloat2 p;
                p.x = xv[i].x * xv[j].x;
                p.y = xv[i].y * xv[j].y;
                ACCUM(8 + idx2(i, j), p);
#pragma unroll
                for (int a = 0; a <= i; ++a) {
                    vfloat2 t;
                    t.x = xv[a].x * p.x;
                    t.y = xv[a].y * p.y;
                    ACCUM(44 + idx3(a, i, j), t);
                }
            }
        }

#pragma unroll
        for (int o = 0; o < CPG; ++o)
            __builtin_nontemporal_store(acc[o], &o2[(size_t)o * HW2 + q]);
    }
}

extern "C" void kernel_launch(void* const* d_in, const int* in_sizes, int n_in,
                              void* d_out, int out_size, void* d_ws, size_t ws_size,
                              hipStream_t stream) {
    const float* x  = (const float*)d_in[0];
    const float* w1 = (const float*)d_in[1];
    const float* b1 = (const float*)d_in[2];
    const float* w2 = (const float*)d_in[3];
    const float* b2 = (const float*)d_in[4];
    const float* w3 = (const float*)d_in[5];
    const float* b3 = (const float*)d_in[6];
    float* out = (float*)d_out;

    dim3 grid(2, NGRP, NB);
    dim3 block(256);
    hoaf_kernel<<<grid, block, 0, stream>>>(x, w1, b1, w2, b2, w3, b3, out);
}

// Round 5
// 157.867 us; speedup vs baseline: 26.0054x; 26.0054x over previous
//
#include <hip/hip_runtime.h>

#define CPG 8
#define NGRP 32
#define NB 16
#define HW 3136
#define HW4 784      // HW in float4 units
#define N2 36
#define N3 120

typedef float vfloat4 __attribute__((ext_vector_type(4)));

__host__ __device__ constexpr int idx2(int i, int j) {
    return i * CPG - i * (i - 1) / 2 + (j - i);
}
__host__ __device__ constexpr int idx3(int a, int b, int c) {
    int base = 0;
    for (int t = 0; t < a; ++t) { int m = CPG - t; base += m * (m + 1) / 2; }
    for (int t = a; t < b; ++t) base += CPG - t;
    return base + (c - b);
}

__device__ inline vfloat4 splat4(float s) { return (vfloat4){s, s, s, s}; }

// feature T (vfloat4 = 4 pixels) x wt[F][0..8): two broadcast ds_read_b128 + 32 fmac
#define ACCUM(F, T) do {                                                       \
    const vfloat4 wa = *reinterpret_cast<const vfloat4*>(&wt[(F)][0]);         \
    const vfloat4 wb = *reinterpret_cast<const vfloat4*>(&wt[(F)][4]);         \
    acc[0] += wa.x * (T); acc[1] += wa.y * (T);                                \
    acc[2] += wa.z * (T); acc[3] += wa.w * (T);                                \
    acc[4] += wb.x * (T); acc[5] += wb.y * (T);                                \
    acc[6] += wb.z * (T); acc[7] += wb.w * (T);                                \
} while (0)

// scheduler fence: nothing may cross (defeats mass ds_read hoisting -> no spill)
#define FENCE() __builtin_amdgcn_sched_barrier(0)

__global__ __launch_bounds__(256, 3) void hoaf_kernel(
    const float* __restrict__ x,
    const float* __restrict__ w1, const float* __restrict__ b1,
    const float* __restrict__ w2, const float* __restrict__ b2,
    const float* __restrict__ w3, const float* __restrict__ b3,
    float* __restrict__ out)
{
    // wt[f][o]: f 0-7 deg1, 8-43 deg2, 44-163 deg3, 164 = summed bias
    __shared__ __align__(16) float wt[165][8];

    const int tid   = threadIdx.x;
    const int chunk = blockIdx.x;   // 0..1
    const int g     = blockIdx.y;   // block-uniform group
    const int b     = blockIdx.z;

    for (int idx = tid; idx < 165 * 8; idx += 256) {
        const int f = idx >> 3, o = idx & 7;
        const int ch = g * CPG + o;
        float v;
        if (f < 8)        v = w1[ch * CPG + f];
        else if (f < 44)  v = w2[ch * N2 + (f - 8)];
        else if (f < 164) v = w3[ch * N3 + (f - 44)];
        else              v = b1[ch] + b2[ch] + b3[ch];
        wt[f][o] = v;
    }
    __syncthreads();

    // bias in registers, hoisted out of the pixel loop
    const vfloat4 b_lo = *reinterpret_cast<const vfloat4*>(&wt[164][0]);
    const vfloat4 b_hi = *reinterpret_cast<const vfloat4*>(&wt[164][4]);

    const size_t base = ((size_t)(b * NGRP + g) * CPG) * HW;
    const vfloat4* x4 = (const vfloat4*)(x + base);
    vfloat4*       o4 = (vfloat4*)(out + base);

    const int qend = chunk ? HW4 : 392;
#pragma unroll 1
    for (int q = tid + chunk * 392; q < qend; q += 256) {
        vfloat4 xv[CPG];
#pragma unroll
        for (int c = 0; c < CPG; ++c) xv[c] = x4[(size_t)c * HW4 + q];

        vfloat4 acc[CPG];
        acc[0] = splat4(b_lo.x); acc[1] = splat4(b_lo.y);
        acc[2] = splat4(b_lo.z); acc[3] = splat4(b_lo.w);
        acc[4] = splat4(b_hi.x); acc[5] = splat4(b_hi.y);
        acc[6] = splat4(b_hi.z); acc[7] = splat4(b_hi.w);

        // degree 1, fenced every 2 features
#pragma unroll
        for (int k = 0; k < CPG; k += 2) {
            ACCUM(k, xv[k]);
            ACCUM(k + 1, xv[k + 1]);
            FENCE();
        }

        // degree 2 & 3: pair product (i<=j) feeds triples (a<=i<=j);
        // one fence per (i,j) group keeps <= ~10 weight b128s in flight
#pragma unroll
        for (int i = 0; i < CPG; ++i) {
#pragma unroll
            for (int j = i; j < CPG; ++j) {
                const vfloat4 p = xv[i] * xv[j];
                ACCUM(8 + idx2(i, j), p);
#pragma unroll
                for (int a = 0; a <= i; ++a) {
                    const vfloat4 t = xv[a] * p;
                    ACCUM(44 + idx3(a, i, j), t);
                }
                FENCE();
            }
        }

#pragma unroll
        for (int o = 0; o < CPG; ++o) o4[(size_t)o * HW4 + q] = acc[o];
    }
}

extern "C" void kernel_launch(void* const* d_in, const int* in_sizes, int n_in,
                              void* d_out, int out_size, void* d_ws, size_t ws_size,
                              hipStream_t stream) {
    const float* x  = (const float*)d_in[0];
    const float* w1 = (const float*)d_in[1];
    const float* b1 = (const float*)d_in[2];
    const float* w2 = (const float*)d_in[3];
    const float* b2 = (const float*)d_in[4];
    const float* w3 = (const float*)d_in[5];
    const float* b3 = (const float*)d_in[6];
    float* out = (float*)d_out;

    dim3 grid(2, NGRP, NB);
    dim3 block(256);
    hoaf_kernel<<<grid, block, 0, stream>>>(x, w1, b1, w2, b2, w3, b3, out);
}